// Round 4
// baseline (233.840 us; speedup 1.0000x reference)
//
#include <hip/hip_runtime.h>

constexpr int S    = 256;
constexpr int NL   = 17;
constexpr int L    = 19;   // start = 17, end = 18
constexpr int CAPB = 16384;
constexpr int CT   = 12;              // tokens per staged chunk (multiple of 4)
constexpr int LSTR = CT * NL + 1;     // 205 dwords per LDS seq slot (odd -> conflict-free)

// per-sequence scratch: fwd state Z, bwd state V (pre el_mid), log-scale factors
__device__ float g_Z[CAPB * 17];
__device__ float g_V[CAPB * 17];
__device__ float g_mf[CAPB];
__device__ float g_mv[CAPB];

typedef const __attribute__((address_space(1))) unsigned int gu32;
typedef __attribute__((address_space(3))) unsigned int lu32;
// coalesced global->LDS: per-lane global addr, LDS dest = uniform base + lane*4
#define GLL(GP, LP) __builtin_amdgcn_global_load_lds((GP), (LP), 4, 0, 0)

// ---------------------------------------------------------------------------
// BIOES sparsity (labels: 0=O; per type t: B=1+4t, I=2+4t, E=3+4t, S=4+4t).
// allowed(to=i, from=j): j in {O,E*,S*} -> i in {O,B*,S*} (9x9 block);
// j in {B_t,I_t} -> i in {I_t,E_t} (16 pair terms). 97 of 289 nonzero.
// ---------------------------------------------------------------------------
#define ROWF(X,i) X(i,0) X(i,3) X(i,4) X(i,7) X(i,8) X(i,11) X(i,12) X(i,15) X(i,16)
#define FWD_ALL(X) \
  ROWF(X,0) ROWF(X,1) ROWF(X,4) ROWF(X,5) ROWF(X,8) ROWF(X,9) ROWF(X,12) ROWF(X,13) ROWF(X,16) \
  X(2,1) X(2,2) X(3,1) X(3,2) X(6,5) X(6,6) X(7,5) X(7,6) \
  X(10,9) X(10,10) X(11,9) X(11,10) X(14,13) X(14,14) X(15,13) X(15,14)

#define ROWB(X,i) X(i,0) X(i,1) X(i,4) X(i,5) X(i,8) X(i,9) X(i,12) X(i,13) X(i,16)
#define BWD_ALL(X) \
  ROWB(X,0) ROWB(X,3) ROWB(X,4) ROWB(X,7) ROWB(X,8) ROWB(X,11) ROWB(X,12) ROWB(X,15) ROWB(X,16) \
  X(1,2) X(1,3) X(2,2) X(2,3) X(5,6) X(5,7) X(6,6) X(6,7) \
  X(9,10) X(9,11) X(10,10) X(10,11) X(13,14) X(13,15) X(14,14) X(14,15)

#define APPLY17(X) X(0) X(1) X(2) X(3) X(4) X(5) X(6) X(7) X(8) X(9) X(10) X(11) X(12) X(13) X(14) X(15) X(16)

#define DCF_F(i,j) const float cf_##i##_##j = __expf(Tg[(i)*19+(j)]);
#define DCF_B(i,j) const float cf_##i##_##j = __expf(Tg[(j)*19+(i)]);

#define DPF(i) float p##i = __expf(Tg[(i)*19+17]);   // E[i, start]
#define DPB(i) float p##i = __expf(Tg[18*19+(i)]);   // E[end, i]

#define DECLSLOT(T) float T##0,T##1,T##2,T##3,T##4,T##5,T##6,T##7,T##8,T##9, \
                          T##10,T##11,T##12,T##13,T##14,T##15,T##16;

// read 17 floats (one token) from this lane's LDS slot at byte offset LAB
#define LOADSLOT(T, LAB) { \
    const float* la_ = (const float*)(ldsB + (LAB)); \
    T##0=la_[0]; T##1=la_[1]; T##2=la_[2]; T##3=la_[3]; T##4=la_[4]; T##5=la_[5]; \
    T##6=la_[6]; T##7=la_[7]; T##8=la_[8]; T##9=la_[9]; T##10=la_[10]; T##11=la_[11]; \
    T##12=la_[12]; T##13=la_[13]; T##14=la_[14]; T##15=la_[15]; T##16=la_[16]; }

#define MKQALL(T) \
    const float q0 = __expf(T##0) * p0;   const float q1 = __expf(T##1) * p1; \
    const float q2 = __expf(T##2) * p2;   const float q3 = __expf(T##3) * p3; \
    const float q4 = __expf(T##4) * p4;   const float q5 = __expf(T##5) * p5; \
    const float q6 = __expf(T##6) * p6;   const float q7 = __expf(T##7) * p7; \
    const float q8 = __expf(T##8) * p8;   const float q9 = __expf(T##9) * p9; \
    const float q10 = __expf(T##10) * p10; const float q11 = __expf(T##11) * p11; \
    const float q12 = __expf(T##12) * p12; const float q13 = __expf(T##13) * p13; \
    const float q14 = __expf(T##14) * p14; const float q15 = __expf(T##15) * p15; \
    const float q16 = __expf(T##16) * p16;

#define FMQ(i,j) cf_##i##_##j * q##j
#define ROW9N(i,a,b,c,d,e,f,g,h,k) \
    const float n##i = (((FMQ(i,a)+FMQ(i,b)) + (FMQ(i,c)+FMQ(i,d))) + \
                        ((FMQ(i,e)+FMQ(i,f)) + (FMQ(i,g)+FMQ(i,h)))) + FMQ(i,k);
#define ROW2N(i,a,b) const float n##i = FMQ(i,a) + FMQ(i,b);

#define MATVEC_F \
    ROW9N(0,0,3,4,7,8,11,12,15,16)  ROW9N(1,0,3,4,7,8,11,12,15,16) \
    ROW9N(4,0,3,4,7,8,11,12,15,16)  ROW9N(5,0,3,4,7,8,11,12,15,16) \
    ROW9N(8,0,3,4,7,8,11,12,15,16)  ROW9N(9,0,3,4,7,8,11,12,15,16) \
    ROW9N(12,0,3,4,7,8,11,12,15,16) ROW9N(13,0,3,4,7,8,11,12,15,16) \
    ROW9N(16,0,3,4,7,8,11,12,15,16) \
    ROW2N(2,1,2)   ROW2N(3,1,2)   ROW2N(6,5,6)   ROW2N(7,5,6) \
    ROW2N(10,9,10) ROW2N(11,9,10) ROW2N(14,13,14) ROW2N(15,13,14)

#define MATVEC_B \
    ROW9N(0,0,1,4,5,8,9,12,13,16)  ROW9N(3,0,1,4,5,8,9,12,13,16) \
    ROW9N(4,0,1,4,5,8,9,12,13,16)  ROW9N(7,0,1,4,5,8,9,12,13,16) \
    ROW9N(8,0,1,4,5,8,9,12,13,16)  ROW9N(11,0,1,4,5,8,9,12,13,16) \
    ROW9N(12,0,1,4,5,8,9,12,13,16) ROW9N(15,0,1,4,5,8,9,12,13,16) \
    ROW9N(16,0,1,4,5,8,9,12,13,16) \
    ROW2N(1,2,3)   ROW2N(2,2,3)   ROW2N(5,6,7)   ROW2N(6,6,7) \
    ROW2N(9,10,11) ROW2N(10,10,11) ROW2N(13,14,15) ROW2N(14,14,15)

#define ASG(i)  p##i = n##i;
#define ASGR(i) p##i = n##i * r_;

#define STORE_P { \
    float* d_ = SC + bc * 17; \
    d_[0]=p0; d_[1]=p1; d_[2]=p2; d_[3]=p3; d_[4]=p4; d_[5]=p5; d_[6]=p6; d_[7]=p7; \
    d_[8]=p8; d_[9]=p9; d_[10]=p10; d_[11]=p11; d_[12]=p12; d_[13]=p13; d_[14]=p14; \
    d_[15]=p15; d_[16]=p16; \
    SM[bc] = m; }

// One step: consume slot CUR (global step T_), lookahead-read NXT from LDS
// byte offset LAB. Lanes past nup run harmless garbage; state stored at trigger.
#define CSTEP(CUR, NXT, T_, LAB, RN, MV) { \
    MKQALL(CUR) \
    LOADSLOT(NXT, LAB) \
    MV \
    if (RN) { \
        float mxA = fmaxf(fmaxf(n0,n1),  fmaxf(n2,n3)); \
        float mxB = fmaxf(fmaxf(n4,n5),  fmaxf(n6,n7)); \
        float mxC = fmaxf(fmaxf(n8,n9),  fmaxf(n10,n11)); \
        float mxD = fmaxf(fmaxf(n12,n13),fmaxf(n14,n15)); \
        float mx  = fmaxf(fmaxf(fmaxf(mxA,mxB), fmaxf(mxC,mxD)), n16); \
        const float r_ = __frcp_rn(mx); \
        m += __logf(mx); \
        APPLY17(ASGR) \
    } else { \
        APPLY17(ASG) \
    } \
    if ((T_) == nup - 1) STORE_P \
}

__device__ __forceinline__ void chainF(const float* __restrict__ logits,
                                       const int* __restrict__ lens,
                                       const float* __restrict__ Tg,
                                       int B, int z, float* ldsbuf)
{
    const int  lane  = threadIdx.x;
    const int  braw  = z * 64 + lane;
    const bool valid = braw < B;
    const int  bc    = valid ? braw : 0;
    const int  len   = lens[bc];
    const int  mid   = len >> 1;
    const int  nup   = valid ? mid : 0;

    FWD_ALL(DCF_F)
    APPLY17(DPF)
    float  m  = 0.0f;
    float* SC = g_Z;
    float* SM = g_mf;
    if (nup == 0 && valid) STORE_P

    int nmax = nup;
    #pragma unroll
    for (int o = 32; o >= 1; o >>= 1) nmax = max(nmax, __shfl_xor(nmax, o));
    const int nch = (nmax + CT - 1) / CT;

    const char* ldsB = (const char*)ldsbuf + lane * (LSTR * 4);
    gu32* gall = (gu32*)(const void*)logits;
    lu32* lall = (lu32*)(void*)ldsbuf;
    DECLSLOT(cv) DECLSLOT(nv)

    for (int c = 0; c < nch; ++c) {
        const int tbase = c * CT;
        // ---- stage chunk: 64 seqs x CT tokens, coalesced (contiguous per seq) ----
        for (int j = 0; j < 64; ++j) {
            const int bj  = z * 64 + j;
            const int bjc = bj < B ? bj : 0;
            gu32* gp = gall + (unsigned)bjc * (S * NL) + (unsigned)tbase * NL + lane;
            lu32* lp = lall + j * LSTR;
            GLL(gp,       lp);
            GLL(gp + 64,  lp + 64);
            GLL(gp + 128, lp + 128);
            if (lane < CT * NL - 192) GLL(gp + 192, lp + 192);
        }
        asm volatile("s_waitcnt vmcnt(0)" ::: "memory");
        LOADSLOT(cv, 0)
        #pragma unroll
        for (int u = 0; u < CT; u += 2) {
            CSTEP(cv, nv, tbase + u,     (u + 1) * 68, false, MATVEC_F)
            CSTEP(nv, cv, tbase + u + 1, (u + 2 < CT ? u + 2 : CT - 1) * 68,
                  ((u & 2) != 0), MATVEC_F)
        }
    }
}

__device__ __forceinline__ void chainB(const float* __restrict__ logits,
                                       const int* __restrict__ lens,
                                       const float* __restrict__ Tg,
                                       int B, int z, float* ldsbuf)
{
    const int  lane  = threadIdx.x;
    const int  braw  = z * 64 + lane;
    const bool valid = braw < B;
    const int  bc    = valid ? braw : 0;
    const int  len   = lens[bc];
    const int  mid   = len >> 1;
    const int  nup   = valid ? (len - 1 - mid) : 0;

    BWD_ALL(DCF_B)
    APPLY17(DPB)
    float  m  = 0.0f;
    float* SC = g_V;
    float* SM = g_mv;
    if (nup == 0 && valid) STORE_P

    int nmax = nup;
    #pragma unroll
    for (int o = 32; o >= 1; o >>= 1) nmax = max(nmax, __shfl_xor(nmax, o));
    const int nch = (nmax + CT - 1) / CT;

    const char* ldsB = (const char*)ldsbuf + lane * (LSTR * 4);
    gu32* gall = (gu32*)(const void*)logits;
    lu32* lall = (lu32*)(void*)ldsbuf;
    DECLSLOT(cv) DECLSLOT(nv)

    for (int c = 0; c < nch; ++c) {
        const int tbase = c * CT;
        // ---- stage: per seq j, CT ascending tokens from btok_j = max(len_j-CT-tbase,0)
        for (int j = 0; j < 64; ++j) {
            const int bj   = z * 64 + j;
            const int bjc  = bj < B ? bj : 0;
            const int lenj = __shfl(len, j);
            const int btok = max(lenj - CT - tbase, 0);
            gu32* gp = gall + (unsigned)bjc * (S * NL) + (unsigned)btok * NL + lane;
            lu32* lp = lall + j * LSTR;
            GLL(gp,       lp);
            GLL(gp + 64,  lp + 64);
            GLL(gp + 128, lp + 128);
            if (lane < CT * NL - 192) GLL(gp + 192, lp + 192);
        }
        asm volatile("s_waitcnt vmcnt(0)" ::: "memory");
        // per-lane descending read offsets within the staged window
        const int bt = max(len - CT - tbase, 0);
        int dof = min(max(len - 1 - tbase - bt, 0), CT - 1);
        LOADSLOT(cv, dof * 68)
        #pragma unroll
        for (int u = 0; u < CT; u += 2) {
            const int dn1 = max(dof - 1, 0);
            CSTEP(cv, nv, tbase + u,     dn1 * 68, false, MATVEC_B)
            const int dn2 = max(dn1 - 1, 0);
            CSTEP(nv, cv, tbase + u + 1, dn2 * 68, ((u & 2) != 0), MATVEC_B)
            dof = dn2;
        }
    }
}

__global__ __launch_bounds__(64, 1)
void crf_chain(const float* __restrict__ logits, const int* __restrict__ lens,
               const float* __restrict__ Tg, int B, int nbh)
{
    __shared__ float ldsbuf[64 * LSTR];   // 52.5 KB
    if ((int)blockIdx.x < nbh) chainF(logits, lens, Tg, B, blockIdx.x, ldsbuf);
    else                       chainB(logits, lens, Tg, B, blockIdx.x - nbh, ldsbuf);
}

// Per sequence: P = sum_i Z_i * exp(logit_mid,i) * V_i ; norm = mf+mv+log P.
// Gold path score swept by all 64 lanes. One wave per sequence.
__global__ __launch_bounds__(64)
void crf_combine(const float* __restrict__ logits, const int* __restrict__ labels,
                 const int* __restrict__ lens, const float* __restrict__ T,
                 float* __restrict__ out, int B)
{
    const int b    = blockIdx.x;
    const int wtid = threadIdx.x;
    const int len  = lens[b];
    const int mid  = len >> 1;

    float prod = 0.0f;
    if (wtid < 17) {
        const float z  = g_Z[b * 17 + wtid];
        const float v  = g_V[b * 17 + wtid];
        const float lg = logits[(size_t)b * (S * NL) + mid * NL + wtid];
        prod = z * v * __expf(lg);
    }
    #pragma unroll
    for (int o = 32; o >= 1; o >>= 1) prod += __shfl_xor(prod, o);
    const float norm = g_mf[b] + g_mv[b] + __logf(prod);

    const int* labp = labels + b * S;
    float gsum = 0.0f;
    for (int c = 0; c < len; c += 64) {
        const int tok = c + wtid;
        if (tok < len) {
            const int lab = labp[tok];
            const int prv = (tok == 0) ? (L - 2) : labp[tok - 1];
            gsum += logits[(size_t)b * (S * NL) + tok * NL + lab] + T[lab * L + prv];
        }
    }
    #pragma unroll
    for (int o = 32; o >= 1; o >>= 1) gsum += __shfl_xor(gsum, o);
    const float gold = gsum + T[(L - 1) * L + labp[len - 1]];

    if (wtid == 0) out[b] = gold - norm;
}

extern "C" void kernel_launch(void* const* d_in, const int* in_sizes, int n_in,
                              void* d_out, int out_size, void* d_ws, size_t ws_size,
                              hipStream_t stream)
{
    (void)n_in; (void)out_size; (void)d_ws; (void)ws_size;
    const float* logits     = (const float*)d_in[0];
    const int*   labels     = (const int*)d_in[1];
    const int*   lens       = (const int*)d_in[2];
    const float* transition = (const float*)d_in[3];
    float*       out        = (float*)d_out;
    const int B   = in_sizes[2];
    const int NBH = (B + 63) / 64;

    crf_chain<<<dim3(2 * NBH), dim3(64), 0, stream>>>(logits, lens, transition, B, NBH);
    crf_combine<<<dim3(B), dim3(64), 0, stream>>>(logits, labels, lens, transition, out, B);
}

// Round 7
// 162.381 us; speedup vs baseline: 1.4401x; 1.4401x over previous
//
#include <hip/hip_runtime.h>

constexpr int S    = 256;
constexpr int NL   = 17;
constexpr int L    = 19;   // start = 17, end = 18
constexpr int CAPB = 16384;

typedef float v4 __attribute__((ext_vector_type(4), aligned(4)));
typedef float f2 __attribute__((ext_vector_type(2)));

__device__ float g_Z[CAPB * 17];
__device__ float g_V[CAPB * 17];
__device__ float g_mf[CAPB];
__device__ float g_mv[CAPB];

__device__ __forceinline__ f2 mkf2(float a, float b) { f2 r; r.x = a; r.y = b; return r; }
__device__ __forceinline__ f2 dup2(float a)          { f2 r; r.x = a; r.y = a; return r; }
#define FMA2(A,B,C) __builtin_elementwise_fma((A),(B),(C))
#define MAX2(A,B)   __builtin_elementwise_max((A),(B))

// ---------------------------------------------------------------------------
// BIOES sparsity: allowed(to=i,from=j): j in {O,E*,S*} -> i in {O,B*,S*}
// (9x9 block) ; j in {B_t,I_t} -> i in {I_t,E_t} (16 pair terms).
// State packed as 8 x float2 row-pairs + scalar p16 (pairing differs fwd/bwd
// so that matvec row-pairs, q-pairs and el-pairs all share one layout):
//   FWD pairs: 0:(0,1) 1:(4,5) 2:(8,9) 3:(12,13) 4:(2,3) 5:(6,7) 6:(10,11) 7:(14,15)
//        wide cols {0,3,4,7,8,11,12,15,16}; narrow cols (1,2)(5,6)(9,10)(13,14)
//   BWD pairs: 0:(0,3) 1:(4,7) 2:(8,11) 3:(12,15) 4:(1,2) 5:(5,6) 6:(9,10) 7:(13,14)
//        wide cols {0,1,4,5,8,9,12,13,16}; narrow cols (2,3)(6,7)(10,11)(14,15)
// fwd cf[i][j] = exp(T[i*19+j]); bwd cf[i][j] = exp(T[j*19+i]).
// ---------------------------------------------------------------------------

// coefficient decls: pair K rows (a,b), col j
#define CWF(K,a,b,j) const f2 c##K##_##j = mkf2(__expf(Tg[(a)*19+(j)]), __expf(Tg[(b)*19+(j)]));
#define CWB(K,a,b,j) const f2 c##K##_##j = mkf2(__expf(Tg[(j)*19+(a)]), __expf(Tg[(j)*19+(b)]));
#define WCOLS_F(X,K,a,b) X(K,a,b,0) X(K,a,b,3) X(K,a,b,4) X(K,a,b,7) X(K,a,b,8) X(K,a,b,11) X(K,a,b,12) X(K,a,b,15) X(K,a,b,16)
#define WCOLS_B(X,K,a,b) X(K,a,b,0) X(K,a,b,1) X(K,a,b,4) X(K,a,b,5) X(K,a,b,8) X(K,a,b,9) X(K,a,b,12) X(K,a,b,13) X(K,a,b,16)

#define COEF_F \
  WCOLS_F(CWF,0,0,1) WCOLS_F(CWF,1,4,5) WCOLS_F(CWF,2,8,9) WCOLS_F(CWF,3,12,13) \
  CWF(4,2,3,1) CWF(4,2,3,2) CWF(5,6,7,5) CWF(5,6,7,6) \
  CWF(6,10,11,9) CWF(6,10,11,10) CWF(7,14,15,13) CWF(7,14,15,14) \
  const float c16_0 = __expf(Tg[16*19+0]);  const float c16_3 = __expf(Tg[16*19+3]); \
  const float c16_4 = __expf(Tg[16*19+4]);  const float c16_7 = __expf(Tg[16*19+7]); \
  const float c16_8 = __expf(Tg[16*19+8]);  const float c16_11 = __expf(Tg[16*19+11]); \
  const float c16_12 = __expf(Tg[16*19+12]); const float c16_15 = __expf(Tg[16*19+15]); \
  const float c16_16 = __expf(Tg[16*19+16]);

#define COEF_B \
  WCOLS_B(CWB,0,0,3) WCOLS_B(CWB,1,4,7) WCOLS_B(CWB,2,8,11) WCOLS_B(CWB,3,12,15) \
  CWB(4,1,2,2) CWB(4,1,2,3) CWB(5,5,6,6) CWB(5,5,6,7) \
  CWB(6,9,10,10) CWB(6,9,10,11) CWB(7,13,14,14) CWB(7,13,14,15) \
  const float c16_0 = __expf(Tg[0*19+16]);  const float c16_1 = __expf(Tg[1*19+16]); \
  const float c16_4 = __expf(Tg[4*19+16]);  const float c16_5 = __expf(Tg[5*19+16]); \
  const float c16_8 = __expf(Tg[8*19+16]);  const float c16_9 = __expf(Tg[9*19+16]); \
  const float c16_12 = __expf(Tg[12*19+16]); const float c16_13 = __expf(Tg[13*19+16]); \
  const float c16_16f = __expf(Tg[16*19+16]);

// initial states
#define PINIT_F \
  f2 vP0 = mkf2(__expf(Tg[0*19+17]),  __expf(Tg[1*19+17])); \
  f2 vP1 = mkf2(__expf(Tg[4*19+17]),  __expf(Tg[5*19+17])); \
  f2 vP2 = mkf2(__expf(Tg[8*19+17]),  __expf(Tg[9*19+17])); \
  f2 vP3 = mkf2(__expf(Tg[12*19+17]), __expf(Tg[13*19+17])); \
  f2 vP4 = mkf2(__expf(Tg[2*19+17]),  __expf(Tg[3*19+17])); \
  f2 vP5 = mkf2(__expf(Tg[6*19+17]),  __expf(Tg[7*19+17])); \
  f2 vP6 = mkf2(__expf(Tg[10*19+17]), __expf(Tg[11*19+17])); \
  f2 vP7 = mkf2(__expf(Tg[14*19+17]), __expf(Tg[15*19+17])); \
  float vp16 = __expf(Tg[16*19+17]);

#define PINIT_B \
  f2 vP0 = mkf2(__expf(Tg[18*19+0]),  __expf(Tg[18*19+3])); \
  f2 vP1 = mkf2(__expf(Tg[18*19+4]),  __expf(Tg[18*19+7])); \
  f2 vP2 = mkf2(__expf(Tg[18*19+8]),  __expf(Tg[18*19+11])); \
  f2 vP3 = mkf2(__expf(Tg[18*19+12]), __expf(Tg[18*19+15])); \
  f2 vP4 = mkf2(__expf(Tg[18*19+1]),  __expf(Tg[18*19+2])); \
  f2 vP5 = mkf2(__expf(Tg[18*19+5]),  __expf(Tg[18*19+6])); \
  f2 vP6 = mkf2(__expf(Tg[18*19+9]),  __expf(Tg[18*19+10])); \
  f2 vP7 = mkf2(__expf(Tg[18*19+13]), __expf(Tg[18*19+14])); \
  float vp16 = __expf(Tg[18*19+16]);

#define DECLSLOT2(T) f2 T##0,T##1,T##2,T##3,T##4,T##5,T##6,T##7; float T##16;

// raw logits -> pair layout (fwd): comps (0,1)(2,3)(4,5)... pairs 0,4,1,5,2,6,3,7
#define LOADF(SL, OFF) { \
    const char* a_ = base + (OFF); \
    const v4 x0 = *(const v4*)(a_);      const v4 x1 = *(const v4*)(a_ + 16); \
    const v4 x2 = *(const v4*)(a_ + 32); const v4 x3 = *(const v4*)(a_ + 48); \
    const float x4 = *(const float*)(a_ + 64); \
    SL##0 = mkf2(x0.x, x0.y); SL##4 = mkf2(x0.z, x0.w); \
    SL##1 = mkf2(x1.x, x1.y); SL##5 = mkf2(x1.z, x1.w); \
    SL##2 = mkf2(x2.x, x2.y); SL##6 = mkf2(x2.z, x2.w); \
    SL##3 = mkf2(x3.x, x3.y); SL##7 = mkf2(x3.z, x3.w); \
    SL##16 = x4; }

// bwd pair layout: pair0=(c0,c3) pair4=(c1,c2) etc.
#define LOADB(SL, OFF) { \
    const char* a_ = base + (OFF); \
    const v4 x0 = *(const v4*)(a_);      const v4 x1 = *(const v4*)(a_ + 16); \
    const v4 x2 = *(const v4*)(a_ + 32); const v4 x3 = *(const v4*)(a_ + 48); \
    const float x4 = *(const float*)(a_ + 64); \
    SL##0 = mkf2(x0.x, x0.w); SL##4 = mkf2(x0.y, x0.z); \
    SL##1 = mkf2(x1.x, x1.w); SL##5 = mkf2(x1.y, x1.z); \
    SL##2 = mkf2(x2.x, x2.w); SL##6 = mkf2(x2.y, x2.z); \
    SL##3 = mkf2(x3.x, x3.w); SL##7 = mkf2(x3.y, x3.z); \
    SL##16 = x4; }

#define MKQ(SL) \
    const f2 Q0 = mkf2(__expf((SL##0).x), __expf((SL##0).y)) * vP0; \
    const f2 Q1 = mkf2(__expf((SL##1).x), __expf((SL##1).y)) * vP1; \
    const f2 Q2 = mkf2(__expf((SL##2).x), __expf((SL##2).y)) * vP2; \
    const f2 Q3 = mkf2(__expf((SL##3).x), __expf((SL##3).y)) * vP3; \
    const f2 Q4 = mkf2(__expf((SL##4).x), __expf((SL##4).y)) * vP4; \
    const f2 Q5 = mkf2(__expf((SL##5).x), __expf((SL##5).y)) * vP5; \
    const f2 Q6 = mkf2(__expf((SL##6).x), __expf((SL##6).y)) * vP6; \
    const f2 Q7 = mkf2(__expf((SL##7).x), __expf((SL##7).y)) * vP7; \
    const float q16 = __expf(SL##16) * vp16;

// q scalar map fwd: q0=Q0.x q1=Q0.y q2=Q4.x q3=Q4.y q4=Q1.x q5=Q1.y q6=Q5.x q7=Q5.y
//                   q8=Q2.x q9=Q2.y q10=Q6.x q11=Q6.y q12=Q3.x q13=Q3.y q14=Q7.x q15=Q7.y
#define DUPS_F \
    const f2 d0=dup2(Q0.x), d3=dup2(Q4.y), d4=dup2(Q1.x), d7=dup2(Q5.y), \
             d8=dup2(Q2.x), d11=dup2(Q6.y), d12=dup2(Q3.x), d15=dup2(Q7.y), d16=dup2(q16); \
    const f2 d1=dup2(Q0.y), d2=dup2(Q4.x), d5=dup2(Q1.y), d6=dup2(Q5.x), \
             d9=dup2(Q2.y), d10=dup2(Q6.x), d13=dup2(Q3.y), d14=dup2(Q7.x);

// q scalar map bwd: q0=Q0.x q3=Q0.y q4=Q1.x q7=Q1.y q8=Q2.x q11=Q2.y q12=Q3.x q15=Q3.y
//                   q1=Q4.x q2=Q4.y q5=Q5.x q6=Q5.y q9=Q6.x q10=Q6.y q13=Q7.x q14=Q7.y
#define DUPS_B \
    const f2 d0=dup2(Q0.x), d1=dup2(Q4.x), d4=dup2(Q1.x), d5=dup2(Q5.x), \
             d8=dup2(Q2.x), d9=dup2(Q6.x), d12=dup2(Q3.x), d13=dup2(Q7.x), d16=dup2(q16); \
    const f2 d2=dup2(Q4.y), d3=dup2(Q0.y), d6=dup2(Q5.y), d7=dup2(Q1.y), \
             d10=dup2(Q6.y), d11=dup2(Q2.y), d14=dup2(Q7.y), d15=dup2(Q3.y);

#define WROW_F(K) \
    f2 N##K = c##K##_0 * d0; \
    N##K = FMA2(c##K##_3,  d3,  N##K); N##K = FMA2(c##K##_4,  d4,  N##K); \
    N##K = FMA2(c##K##_7,  d7,  N##K); N##K = FMA2(c##K##_8,  d8,  N##K); \
    N##K = FMA2(c##K##_11, d11, N##K); N##K = FMA2(c##K##_12, d12, N##K); \
    N##K = FMA2(c##K##_15, d15, N##K); N##K = FMA2(c##K##_16, d16, N##K);

#define WROW_B(K) \
    f2 N##K = c##K##_0 * d0; \
    N##K = FMA2(c##K##_1,  d1,  N##K); N##K = FMA2(c##K##_4,  d4,  N##K); \
    N##K = FMA2(c##K##_5,  d5,  N##K); N##K = FMA2(c##K##_8,  d8,  N##K); \
    N##K = FMA2(c##K##_9,  d9,  N##K); N##K = FMA2(c##K##_12, d12, N##K); \
    N##K = FMA2(c##K##_13, d13, N##K); N##K = FMA2(c##K##_16, d16, N##K);

#define NARROW_F \
    f2 N4 = c4_1 * d1;   N4 = FMA2(c4_2,  d2,  N4); \
    f2 N5 = c5_5 * d5;   N5 = FMA2(c5_6,  d6,  N5); \
    f2 N6 = c6_9 * d9;   N6 = FMA2(c6_10, d10, N6); \
    f2 N7 = c7_13 * d13; N7 = FMA2(c7_14, d14, N7);

#define NARROW_B \
    f2 N4 = c4_2 * d2;   N4 = FMA2(c4_3,  d3,  N4); \
    f2 N5 = c5_6 * d6;   N5 = FMA2(c5_7,  d7,  N5); \
    f2 N6 = c6_10 * d10; N6 = FMA2(c6_11, d11, N6); \
    f2 N7 = c7_14 * d14; N7 = FMA2(c7_15, d15, N7);

#define R16_F \
    float n16 = c16_0 * d0.x; \
    n16 = fmaf(c16_3, d3.x, n16);   n16 = fmaf(c16_4, d4.x, n16); \
    n16 = fmaf(c16_7, d7.x, n16);   n16 = fmaf(c16_8, d8.x, n16); \
    n16 = fmaf(c16_11, d11.x, n16); n16 = fmaf(c16_12, d12.x, n16); \
    n16 = fmaf(c16_15, d15.x, n16); n16 = fmaf(c16_16, d16.x, n16);

#define R16_B \
    float n16 = c16_0 * d0.x; \
    n16 = fmaf(c16_1, d1.x, n16);   n16 = fmaf(c16_4, d4.x, n16); \
    n16 = fmaf(c16_5, d5.x, n16);   n16 = fmaf(c16_8, d8.x, n16); \
    n16 = fmaf(c16_9, d9.x, n16);   n16 = fmaf(c16_12, d12.x, n16); \
    n16 = fmaf(c16_13, d13.x, n16); n16 = fmaf(c16_16f, d16.x, n16);

#define FINISH(RN) \
    if (RN) { \
        const f2 MM = MAX2(MAX2(MAX2(N0,N1), MAX2(N2,N3)), \
                           MAX2(MAX2(N4,N5), MAX2(N6,N7))); \
        const float mx = fmaxf(fmaxf(MM.x, MM.y), n16); \
        const float r_ = __frcp_rn(mx); \
        m += __logf(mx); \
        const f2 R2 = dup2(r_); \
        vP0=N0*R2; vP1=N1*R2; vP2=N2*R2; vP3=N3*R2; \
        vP4=N4*R2; vP5=N5*R2; vP6=N6*R2; vP7=N7*R2; vp16=n16*r_; \
    } else { \
        vP0=N0; vP1=N1; vP2=N2; vP3=N3; vP4=N4; vP5=N5; vP6=N6; vP7=N7; vp16=n16; \
    }

#define STOREF { \
    float* d_ = g_Z + bc * 17; \
    d_[0]=vP0.x;  d_[1]=vP0.y;  d_[2]=vP4.x;  d_[3]=vP4.y; \
    d_[4]=vP1.x;  d_[5]=vP1.y;  d_[6]=vP5.x;  d_[7]=vP5.y; \
    d_[8]=vP2.x;  d_[9]=vP2.y;  d_[10]=vP6.x; d_[11]=vP6.y; \
    d_[12]=vP3.x; d_[13]=vP3.y; d_[14]=vP7.x; d_[15]=vP7.y; \
    d_[16]=vp16;  g_mf[bc]=m; }

#define STOREB { \
    float* d_ = g_V + bc * 17; \
    d_[0]=vP0.x;  d_[3]=vP0.y;  d_[1]=vP4.x;  d_[2]=vP4.y; \
    d_[4]=vP1.x;  d_[7]=vP1.y;  d_[5]=vP5.x;  d_[6]=vP5.y; \
    d_[8]=vP2.x;  d_[11]=vP2.y; d_[9]=vP6.x;  d_[10]=vP6.y; \
    d_[12]=vP3.x; d_[15]=vP3.y; d_[13]=vP7.x; d_[14]=vP7.y; \
    d_[16]=vp16;  g_mv[bc]=m; }

#define CSTEPF(SL, T_, OFFV, RN) { \
    MKQ(SL) \
    OFFV += 136; \
    LOADF(SL, OFFV) \
    DUPS_F \
    WROW_F(0) WROW_F(1) WROW_F(2) WROW_F(3) \
    NARROW_F \
    R16_F \
    FINISH(RN) \
    if ((T_) == nup - 1) STOREF \
}

#define CSTEPB(SL, T_, OFFV, RN) { \
    MKQ(SL) \
    OFFV -= 136; \
    if (OFFV < capLo) OFFV = capLo; \
    LOADB(SL, OFFV) \
    DUPS_B \
    WROW_B(0) WROW_B(1) WROW_B(2) WROW_B(3) \
    NARROW_B \
    R16_B \
    FINISH(RN) \
    if ((T_) == nup - 1) STOREB \
}

__device__ __forceinline__ void chainF(const float* __restrict__ logits,
                                       const int* __restrict__ lens,
                                       const float* __restrict__ Tg, int B, int z)
{
    const int  lane  = threadIdx.x;
    const int  braw  = z * 64 + lane;
    const bool valid = braw < B;
    const int  bc    = valid ? braw : 0;
    const int  len   = lens[bc];
    const int  mid   = len >> 1;
    const int  nup   = valid ? mid : 0;

    COEF_F
    PINIT_F
    float m = 0.0f;
    if (nup == 0 && valid) STOREF

    int nmax = nup;
    #pragma unroll
    for (int o = 32; o >= 1; o >>= 1) nmax = max(nmax, __shfl_xor(nmax, o));
    nmax = (nmax + 3) & ~3;

    const char* base = (const char*)logits;
    const int   sb4  = bc * (S * NL * 4);
    int offA = sb4, offB = sb4 + 68;

    DECLSLOT2(sA) DECLSLOT2(sB)
    LOADF(sA, offA) LOADF(sB, offB)

    for (int tb = 0; tb < nmax; tb += 4) {
        CSTEPF(sA, tb,     offA, 0)
        CSTEPF(sB, tb + 1, offB, 0)
        CSTEPF(sA, tb + 2, offA, 0)
        CSTEPF(sB, tb + 3, offB, 1)   // renorm at t % 4 == 3
    }
}

__device__ __forceinline__ void chainB(const float* __restrict__ logits,
                                       const int* __restrict__ lens,
                                       const float* __restrict__ Tg, int B, int z)
{
    const int  lane  = threadIdx.x;
    const int  braw  = z * 64 + lane;
    const bool valid = braw < B;
    const int  bc    = valid ? braw : 0;
    const int  len   = lens[bc];
    const int  mid   = len >> 1;
    const int  nup   = valid ? (len - 1 - mid) : 0;

    COEF_B
    PINIT_B
    float m = 0.0f;
    if (nup == 0 && valid) STOREB

    int nmax = nup;
    #pragma unroll
    for (int o = 32; o >= 1; o >>= 1) nmax = max(nmax, __shfl_xor(nmax, o));
    nmax = (nmax + 3) & ~3;

    const char* base  = (const char*)logits;
    const int   sb4   = bc * (S * NL * 4);
    const int   capLo = sb4;
    int offA = sb4 + max(len - 1, 0) * 68;
    int offB = sb4 + max(len - 2, 0) * 68;

    DECLSLOT2(sA) DECLSLOT2(sB)
    LOADB(sA, offA) LOADB(sB, offB)

    for (int tb = 0; tb < nmax; tb += 4) {
        CSTEPB(sA, tb,     offA, 0)
        CSTEPB(sB, tb + 1, offB, 0)
        CSTEPB(sA, tb + 2, offA, 0)
        CSTEPB(sB, tb + 3, offB, 1)
    }
}

__global__ __launch_bounds__(64, 1)
void crf_chain(const float* __restrict__ logits, const int* __restrict__ lens,
               const float* __restrict__ Tg, int B, int nbh)
{
    if ((int)blockIdx.x < nbh) chainF(logits, lens, Tg, B, blockIdx.x);
    else                       chainB(logits, lens, Tg, B, blockIdx.x - nbh);
}

// Per sequence: P = sum_i Z_i * exp(logit_mid,i) * V_i ; norm = mf+mv+log P.
// Gold path score swept by all 64 lanes. One wave per sequence.
__global__ __launch_bounds__(64)
void crf_combine(const float* __restrict__ logits, const int* __restrict__ labels,
                 const int* __restrict__ lens, const float* __restrict__ T,
                 float* __restrict__ out, int B)
{
    const int b    = blockIdx.x;
    const int wtid = threadIdx.x;
    const int len  = lens[b];
    const int mid  = len >> 1;

    float prod = 0.0f;
    if (wtid < 17) {
        const float z  = g_Z[b * 17 + wtid];
        const float v  = g_V[b * 17 + wtid];
        const float lg = logits[(size_t)b * (S * NL) + mid * NL + wtid];
        prod = z * v * __expf(lg);
    }
    #pragma unroll
    for (int o = 32; o >= 1; o >>= 1) prod += __shfl_xor(prod, o);
    const float norm = g_mf[b] + g_mv[b] + __logf(prod);

    const int* labp = labels + b * S;
    float gsum = 0.0f;
    for (int c = 0; c < len; c += 64) {
        const int tok = c + wtid;
        if (tok < len) {
            const int lab = labp[tok];
            const int prv = (tok == 0) ? (L - 2) : labp[tok - 1];
            gsum += logits[(size_t)b * (S * NL) + tok * NL + lab] + T[lab * L + prv];
        }
    }
    #pragma unroll
    for (int o = 32; o >= 1; o >>= 1) gsum += __shfl_xor(gsum, o);
    const float gold = gsum + T[(L - 1) * L + labp[len - 1]];

    if (wtid == 0) out[b] = gold - norm;
}

extern "C" void kernel_launch(void* const* d_in, const int* in_sizes, int n_in,
                              void* d_out, int out_size, void* d_ws, size_t ws_size,
                              hipStream_t stream)
{
    (void)n_in; (void)out_size; (void)d_ws; (void)ws_size;
    const float* logits     = (const float*)d_in[0];
    const int*   labels     = (const int*)d_in[1];
    const int*   lens       = (const int*)d_in[2];
    const float* transition = (const float*)d_in[3];
    float*       out        = (float*)d_out;
    const int B   = in_sizes[2];
    const int NBH = (B + 63) / 64;

    crf_chain<<<dim3(2 * NBH), dim3(64), 0, stream>>>(logits, lens, transition, B, NBH);
    crf_combine<<<dim3(B), dim3(64), 0, stream>>>(logits, labels, lens, transition, out, B);
}

// Round 8
// 148.376 us; speedup vs baseline: 1.5760x; 1.0944x over previous
//
#include <hip/hip_runtime.h>

constexpr int S    = 256;
constexpr int NL   = 17;
constexpr int L    = 19;   // start = 17, end = 18
constexpr int CAPB = 16384;

typedef float v4 __attribute__((ext_vector_type(4), aligned(4)));

__device__ float g_Z[CAPB * 17];
__device__ float g_V[CAPB * 17];
__device__ float g_mf[CAPB];
__device__ float g_mv[CAPB];

// ---------------------------------------------------------------------------
// 2 lanes per sequence. Even lane (P=0) owns states 0..7 (+pad slot 8);
// odd lane (P=1) owns states 8..16. BIOES sparsity:
//   fwd wide rows {0,1,4,5,8,9,12,13,16} read cols FS={0,3,4,7,8,11,12,15,16}
//   fwd narrow rows (2,3)<-q1,q2 (6,7)<-q5,q6 (10,11)<-q9,q10 (14,15)<-q13,q14
//   bwd wide rows FS read cols WS={0,1,4,5,8,9,12,13,16}
//   bwd narrow rows (1,2)<-q2,q3 (5,6)<-q6,q7 (9,10)<-q10,q11 (13,14)<-q14,q15
// Per-lane local index j: P0 state j (j<8), P1 state 8+j. Both parities share
// identical LOCAL positions for wide-out rows, exchange set, narrow in/out:
//   fwd: E={0,3,4,7,8}  WO={0,1,4,5,8}  NO={2,3,6,7}  NI=(1,2)/(5,6)
//   bwd: E={0,1,4,5,8}  WO={0,3,4,7,8}  NO={1,2,5,6}  NI=(2,3)/(6,7)
// Wide row = sum_i A[r][i]*own_q[E[i]] + sum_i B[r][i]*recv_q[E[i]], where
// recv = __shfl_xor(own,1). Pad slots carry coef 0 and value 0.
// fwd cf[i][j]=exp(T[i*19+j]); bwd cf[i][j]=exp(T[j*19+i]).
// ---------------------------------------------------------------------------

#define CSTEP2(SL, TT, OFFV, RN) { \
    float q[9]; \
    _Pragma("unroll") for (int j = 0; j < 9; ++j) q[j] = __expf(SL[j]) * p[j]; \
    OFFV += ADV; \
    if (BWD) OFFV = OFFV < sb4 ? sb4 : OFFV; \
    loadSlot(SL, OFFV); \
    float ow[5], rv[5]; \
    _Pragma("unroll") for (int i = 0; i < 5; ++i) ow[i] = q[Ee[i]]; \
    _Pragma("unroll") for (int i = 0; i < 5; ++i) rv[i] = __shfl_xor(ow[i], 1); \
    float N[9]; \
    _Pragma("unroll") for (int r = 0; r < 5; ++r) { \
        float a = A[r][0] * ow[0]; \
        _Pragma("unroll") for (int i = 1; i < 5; ++i) a = fmaf(A[r][i], ow[i], a); \
        _Pragma("unroll") for (int i = 0; i < 5; ++i) a = fmaf(Bc[r][i], rv[i], a); \
        N[WO[r]] = a; \
    } \
    _Pragma("unroll") for (int r = 0; r < 4; ++r) \
        N[NO[r]] = fmaf(NC[r][1], q[NIb[r]], NC[r][0] * q[NIa[r]]); \
    if (RN) { \
        float mx = N[0]; \
        _Pragma("unroll") for (int j = 1; j < 9; ++j) mx = fmaxf(mx, N[j]); \
        mx = fmaxf(mx, __shfl_xor(mx, 1)); \
        const float rr = __frcp_rn(mx); \
        m += __logf(mx); \
        _Pragma("unroll") for (int j = 0; j < 9; ++j) p[j] = N[j] * rr; \
    } else { \
        _Pragma("unroll") for (int j = 0; j < 9; ++j) p[j] = N[j]; \
    } \
    if ((TT) == nup - 1) storeP(); \
}

template <int BWD>
__device__ __forceinline__ void chain2(const float* __restrict__ logits,
                                       const int* __restrict__ lens,
                                       const float* __restrict__ Tg, int B, int z)
{
    const int  wtid  = threadIdx.x;
    const int  P     = wtid & 1;
    const int  braw  = z * 32 + (wtid >> 1);
    const bool valid = braw < B;
    const int  bc    = valid ? braw : 0;
    const int  len   = lens[bc];
    const int  mid   = len >> 1;
    const int  nup   = valid ? (BWD ? (len - 1 - mid) : mid) : 0;

    // local-index tables (compile-time)
    constexpr int Ee[5]  = {0, BWD ? 1 : 3, 4, BWD ? 5 : 7, 8};
    constexpr int WO[5]  = {0, BWD ? 3 : 1, 4, BWD ? 7 : 5, 8};
    constexpr int NO[4]  = {BWD ? 1 : 2, BWD ? 2 : 3, BWD ? 5 : 6, BWD ? 6 : 7};
    constexpr int NIa[4] = {BWD ? 2 : 1, BWD ? 2 : 1, BWD ? 6 : 5, BWD ? 6 : 5};
    constexpr int NIb[4] = {BWD ? 3 : 2, BWD ? 3 : 2, BWD ? 7 : 6, BWD ? 7 : 6};

    // local slot j -> global state (or -1 = pad)
    auto stOf = [&](int par, int j) -> int {
        return par ? (8 + j) : (j < 8 ? j : -1);
    };
    auto expT = [&](int r, int c) -> float {
        return __expf(BWD ? Tg[c * 19 + r] : Tg[r * 19 + c]);
    };

    // per-lane coefficients (values differ by parity; code is uniform)
    float A[5][5], Bc[5][5], NC[4][2];
    #pragma unroll
    for (int r = 0; r < 5; ++r) {
        const int rw  = stOf(P, WO[r]);
        const int rwc = rw < 0 ? 0 : rw;
        #pragma unroll
        for (int i = 0; i < 5; ++i) {
            const int sa = stOf(P, Ee[i]);
            const int sb = stOf(1 - P, Ee[i]);
            A[r][i]  = (rw >= 0 && sa >= 0) ? expT(rwc, sa < 0 ? 0 : sa) : 0.0f;
            Bc[r][i] = (rw >= 0 && sb >= 0) ? expT(rwc, sb < 0 ? 0 : sb) : 0.0f;
        }
    }
    #pragma unroll
    for (int r = 0; r < 4; ++r) {
        const int rn = stOf(P, NO[r]);       // never pad
        NC[r][0] = expT(rn, stOf(P, NIa[r]));
        NC[r][1] = expT(rn, stOf(P, NIb[r]));
    }

    // init state: fwd p_s = exp(T[s,start]); bwd v_s = exp(T[end,s]); pad = 0
    float p[9];
    #pragma unroll
    for (int j = 0; j < 9; ++j) {
        const int s  = stOf(P, j);
        const int sc = s < 0 ? 0 : s;
        p[j] = s < 0 ? 0.0f
                     : __expf(BWD ? Tg[18 * 19 + sc] : Tg[sc * 19 + 17]);
    }
    float m = 0.0f;

    float* SC = BWD ? g_V : g_Z;
    float* SM = BWD ? g_mv : g_mf;
    auto storeP = [&]() {
        float* d_ = SC + bc * 17 + (P ? 8 : 0);
        #pragma unroll
        for (int j = 0; j < 9; ++j)
            if (j < 8 || P) d_[j] = p[j];
        if (P) SM[bc] = m;
    };

    if (nup == 0 && valid) storeP();

    int nmax = nup;
    #pragma unroll
    for (int o = 32; o >= 1; o >>= 1) nmax = max(nmax, __shfl_xor(nmax, o));
    nmax = (nmax + 3) & ~3;

    const char* baseb = (const char*)logits;
    const int   sb4   = bc * (S * NL * 4);
    const int   ADV   = BWD ? -272 : 272;
    const int   poff  = P ? 32 : 0;

    auto loadSlot = [&](float (&sl)[9], int off) {
        const char* a  = baseb + off + poff;
        const v4    x0 = *(const v4*)(a);
        const v4    x1 = *(const v4*)(a + 16);
        const float x2 = *(const float*)(baseb + off + (P ? 64 : 0));
        sl[0] = x0.x; sl[1] = x0.y; sl[2] = x0.z; sl[3] = x0.w;
        sl[4] = x1.x; sl[5] = x1.y; sl[6] = x1.z; sl[7] = x1.w;
        sl[8] = P ? x2 : 0.0f;   // P0 pad: q[8]=exp(0)*0=0
    };

    int offA, offB2, offC, offD;
    if (BWD) {
        const int t0 = len - 1;
        offA  = sb4 + max(t0,     0) * 68;
        offB2 = sb4 + max(t0 - 1, 0) * 68;
        offC  = sb4 + max(t0 - 2, 0) * 68;
        offD  = sb4 + max(t0 - 3, 0) * 68;
    } else {
        offA = sb4; offB2 = sb4 + 68; offC = sb4 + 136; offD = sb4 + 204;
    }

    float slA[9], slB[9], slC[9], slD[9];
    loadSlot(slA, offA); loadSlot(slB, offB2);
    loadSlot(slC, offC); loadSlot(slD, offD);

    for (int tb = 0; tb < nmax; tb += 4) {
        CSTEP2(slA, tb,     offA,  0)
        CSTEP2(slB, tb + 1, offB2, 0)
        CSTEP2(slC, tb + 2, offC,  0)
        CSTEP2(slD, tb + 3, offD,  1)   // renorm at t % 4 == 3
    }
}

__global__ __launch_bounds__(64, 1)
void crf_chain(const float* __restrict__ logits, const int* __restrict__ lens,
               const float* __restrict__ Tg, int B, int nz)
{
    if ((int)blockIdx.x < nz) chain2<0>(logits, lens, Tg, B, blockIdx.x);
    else                      chain2<1>(logits, lens, Tg, B, blockIdx.x - nz);
}

// Per sequence: P = sum_i Z_i * exp(logit_mid,i) * V_i ; norm = mf+mv+log P.
// Gold path score swept by all 64 lanes. One wave per sequence.
__global__ __launch_bounds__(64)
void crf_combine(const float* __restrict__ logits, const int* __restrict__ labels,
                 const int* __restrict__ lens, const float* __restrict__ T,
                 float* __restrict__ out, int B)
{
    const int b    = blockIdx.x;
    const int wtid = threadIdx.x;
    const int len  = lens[b];
    const int mid  = len >> 1;

    float prod = 0.0f;
    if (wtid < 17) {
        const float z  = g_Z[b * 17 + wtid];
        const float v  = g_V[b * 17 + wtid];
        const float lg = logits[(size_t)b * (S * NL) + mid * NL + wtid];
        prod = z * v * __expf(lg);
    }
    #pragma unroll
    for (int o = 32; o >= 1; o >>= 1) prod += __shfl_xor(prod, o);
    const float norm = g_mf[b] + g_mv[b] + __logf(prod);

    const int* labp = labels + b * S;
    float gsum = 0.0f;
    for (int c = 0; c < len; c += 64) {
        const int tok = c + wtid;
        if (tok < len) {
            const int lab = labp[tok];
            const int prv = (tok == 0) ? (L - 2) : labp[tok - 1];
            gsum += logits[(size_t)b * (S * NL) + tok * NL + lab] + T[lab * L + prv];
        }
    }
    #pragma unroll
    for (int o = 32; o >= 1; o >>= 1) gsum += __shfl_xor(gsum, o);
    const float gold = gsum + T[(L - 1) * L + labp[len - 1]];

    if (wtid == 0) out[b] = gold - norm;
}

extern "C" void kernel_launch(void* const* d_in, const int* in_sizes, int n_in,
                              void* d_out, int out_size, void* d_ws, size_t ws_size,
                              hipStream_t stream)
{
    (void)n_in; (void)out_size; (void)d_ws; (void)ws_size;
    const float* logits     = (const float*)d_in[0];
    const int*   labels     = (const int*)d_in[1];
    const int*   lens       = (const int*)d_in[2];
    const float* transition = (const float*)d_in[3];
    float*       out        = (float*)d_out;
    const int B  = in_sizes[2];
    const int NZ = (B + 31) / 32;

    crf_chain<<<dim3(2 * NZ), dim3(64), 0, stream>>>(logits, lens, transition, B, NZ);
    crf_combine<<<dim3(B), dim3(64), 0, stream>>>(logits, labels, lens, transition, out, B);
}

// Round 9
// 135.759 us; speedup vs baseline: 1.7225x; 1.0929x over previous
//
#include <hip/hip_runtime.h>

constexpr int S    = 256;
constexpr int NL   = 17;
constexpr int L    = 19;   // start = 17, end = 18
constexpr int CAPB = 16384;

typedef float v4 __attribute__((ext_vector_type(4), aligned(4)));

__device__ float g_Z[CAPB * 17];
__device__ float g_V[CAPB * 17];
__device__ float g_mf[CAPB];
__device__ float g_mv[CAPB];

// ---------------------------------------------------------------------------
// 4 lanes per sequence (one quad). Lane P owns type t=P: states
// {B,I,E,S}_t = {1+4t .. 4+4t} (local slots 1..4) + replicated O (slot 0).
// fwd: wide rows {O, B_t, S_t} read {O} ∪ {E_u, S_u : u}; narrow {I_t,E_t}
//   read {B_t,I_t} (lane-local).
// bwd (E^T): wide rows {O, E_t, S_t} read {O} ∪ {B_u, S_u}; narrow {B_t,I_t}
//   read {I_t,E_t} (local).
// Exchange: quad all-gather of own (E,S)/(B,S) pair = 6 shfl_xor (DPP-cheap).
// Lane loads: one dwordx4 (its 4 logits, contiguous) + O scalar (quad-shared).
// Renorm every 4 steps: quad-max via 2 shfl_xor (rr, m quad-uniform).
// Relative source order: register k holds type u = t ^ k; coefficients are
// loaded in the same rotated order, so code is lane-uniform.
// fwd cf[to][from]=exp(T[to*19+from]); bwd = exp(T[from*19+to]).
// ---------------------------------------------------------------------------

#define CSTEP4(SL, TT, OFFV, RN) { \
    const float q0 = __expf(SL[0]) * p[0]; \
    const float q1 = __expf(SL[1]) * p[1]; \
    const float q2 = __expf(SL[2]) * p[2]; \
    const float q3 = __expf(SL[3]) * p[3]; \
    const float q4 = __expf(SL[4]) * p[4]; \
    OFFV += ADV; \
    if (BWD) OFFV = OFFV < sb4 ? sb4 : OFFV; \
    loadSlot(SL, OFFV); \
    const float a0 = BWD ? q1 : q3;   /* own E (fwd) / B (bwd) */ \
    const float b0 = q4;              /* own S */ \
    const float a1 = __shfl_xor(a0, 1), b1 = __shfl_xor(b0, 1); \
    const float a2 = __shfl_xor(a0, 2), b2 = __shfl_xor(b0, 2); \
    const float a3 = __shfl_xor(a1, 2), b3 = __shfl_xor(b1, 2); \
    float w0, w1, w2; \
    { float acc = cfO[0] * q0; \
      acc = fmaf(cfE[0][0], a0, acc); acc = fmaf(cfS[0][0], b0, acc); \
      acc = fmaf(cfE[0][1], a1, acc); acc = fmaf(cfS[0][1], b1, acc); \
      acc = fmaf(cfE[0][2], a2, acc); acc = fmaf(cfS[0][2], b2, acc); \
      acc = fmaf(cfE[0][3], a3, acc); acc = fmaf(cfS[0][3], b3, acc); w0 = acc; } \
    { float acc = cfO[1] * q0; \
      acc = fmaf(cfE[1][0], a0, acc); acc = fmaf(cfS[1][0], b0, acc); \
      acc = fmaf(cfE[1][1], a1, acc); acc = fmaf(cfS[1][1], b1, acc); \
      acc = fmaf(cfE[1][2], a2, acc); acc = fmaf(cfS[1][2], b2, acc); \
      acc = fmaf(cfE[1][3], a3, acc); acc = fmaf(cfS[1][3], b3, acc); w1 = acc; } \
    { float acc = cfO[2] * q0; \
      acc = fmaf(cfE[2][0], a0, acc); acc = fmaf(cfS[2][0], b0, acc); \
      acc = fmaf(cfE[2][1], a1, acc); acc = fmaf(cfS[2][1], b1, acc); \
      acc = fmaf(cfE[2][2], a2, acc); acc = fmaf(cfS[2][2], b2, acc); \
      acc = fmaf(cfE[2][3], a3, acc); acc = fmaf(cfS[2][3], b3, acc); w2 = acc; } \
    const float ni0 = BWD ? q2 : q1;  /* narrow inputs: fwd (B,I), bwd (I,E) */ \
    const float ni1 = BWD ? q3 : q2; \
    const float nr0 = fmaf(ncb0, ni1, nca0 * ni0); \
    const float nr1 = fmaf(ncb1, ni1, nca1 * ni0); \
    float N0 = w0, N1, N2, N3, N4 = w2; \
    if (BWD) { N3 = w1; N1 = nr0; N2 = nr1; } \
    else     { N1 = w1; N2 = nr0; N3 = nr1; } \
    if (RN) { \
        float mx = fmaxf(fmaxf(N0, N1), fmaxf(N2, fmaxf(N3, N4))); \
        mx = fmaxf(mx, __shfl_xor(mx, 1)); \
        mx = fmaxf(mx, __shfl_xor(mx, 2)); \
        const float rr = __frcp_rn(mx); \
        m += __logf(mx); \
        p[0] = N0 * rr; p[1] = N1 * rr; p[2] = N2 * rr; \
        p[3] = N3 * rr; p[4] = N4 * rr; \
    } else { \
        p[0] = N0; p[1] = N1; p[2] = N2; p[3] = N3; p[4] = N4; \
    } \
    if ((TT) == nup - 1) storeP(); \
}

template <int BWD>
__device__ __forceinline__ void chain4(const float* __restrict__ logits,
                                       const int* __restrict__ lens,
                                       const float* __restrict__ Tg, int B, int z)
{
    const int  wtid  = threadIdx.x;
    const int  t     = wtid & 3;            // owned type
    const int  braw  = z * 16 + (wtid >> 2);
    const bool valid = braw < B;
    const int  bc    = valid ? braw : 0;
    const int  len   = lens[bc];
    const int  mid   = len >> 1;
    const int  nup   = valid ? (BWD ? (len - 1 - mid) : mid) : 0;

    auto expT = [&](int r, int c) -> float {
        return __expf(BWD ? Tg[c * 19 + r] : Tg[r * 19 + c]);
    };

    // wide-to rows: fwd {O, B_t, S_t}; bwd {O, E_t, S_t}
    const int rowW0 = 0;
    const int rowW1 = BWD ? 3 + 4 * t : 1 + 4 * t;
    const int rowW2 = 4 + 4 * t;

    float cfO[3], cfE[3][4], cfS[3][4];
    #pragma unroll
    for (int r = 0; r < 3; ++r) {
        const int rw = r == 0 ? rowW0 : (r == 1 ? rowW1 : rowW2);
        cfO[r] = expT(rw, 0);
        #pragma unroll
        for (int k = 0; k < 4; ++k) {
            const int u  = t ^ k;
            const int eu = BWD ? 1 + 4 * u : 3 + 4 * u;   // B_u / E_u
            const int su = 4 + 4 * u;                     // S_u
            cfE[r][k] = expT(rw, eu);
            cfS[r][k] = expT(rw, su);
        }
    }
    // narrow rows: fwd I,E <- (B,I); bwd B,I <- (I,E)
    const int nrow0 = BWD ? 1 + 4 * t : 2 + 4 * t;
    const int nrow1 = BWD ? 2 + 4 * t : 3 + 4 * t;
    const int ncA   = BWD ? 2 + 4 * t : 1 + 4 * t;
    const int ncB   = BWD ? 3 + 4 * t : 2 + 4 * t;
    const float nca0 = expT(nrow0, ncA), ncb0 = expT(nrow0, ncB);
    const float nca1 = expT(nrow1, ncA), ncb1 = expT(nrow1, ncB);

    // init: fwd p_s = exp(T[s,start]); bwd p_s = exp(T[end,s]); slot0 = O
    float p[5];
    p[0] = BWD ? __expf(Tg[18 * 19 + 0]) : __expf(Tg[0 * 19 + 17]);
    #pragma unroll
    for (int i = 0; i < 4; ++i) {
        const int s = 1 + 4 * t + i;
        p[1 + i] = BWD ? __expf(Tg[18 * 19 + s]) : __expf(Tg[s * 19 + 17]);
    }
    float m = 0.0f;

    auto storeP = [&]() {
        float* d_ = (BWD ? g_V : g_Z) + bc * 17;
        d_[1 + 4 * t] = p[1]; d_[2 + 4 * t] = p[2];
        d_[3 + 4 * t] = p[3]; d_[4 + 4 * t] = p[4];
        if (t == 0) { d_[0] = p[0]; (BWD ? g_mv : g_mf)[bc] = m; }
    };
    if (nup == 0 && valid) storeP();

    int nmax = nup;
    #pragma unroll
    for (int o = 32; o >= 1; o >>= 1) nmax = max(nmax, __shfl_xor(nmax, o));
    nmax = (nmax + 3) & ~3;

    const char* baseb = (const char*)logits;
    const int   sb4   = bc * (S * NL * 4);
    const int   ADV   = BWD ? -272 : 272;
    const int   lo4   = 4 + 16 * t;   // byte offset of states 1+4t..4+4t

    auto loadSlot = [&](float (&sl)[5], int off) {
        const v4    x = *(const v4*)(baseb + off + lo4);
        const float o = *(const float*)(baseb + off);     // O, quad-shared
        sl[0] = o; sl[1] = x.x; sl[2] = x.y; sl[3] = x.z; sl[4] = x.w;
    };

    int offA, offB2, offC, offD;
    if (BWD) {
        const int t0 = len - 1;
        offA  = sb4 + max(t0,     0) * 68;
        offB2 = sb4 + max(t0 - 1, 0) * 68;
        offC  = sb4 + max(t0 - 2, 0) * 68;
        offD  = sb4 + max(t0 - 3, 0) * 68;
    } else {
        offA = sb4; offB2 = sb4 + 68; offC = sb4 + 136; offD = sb4 + 204;
    }

    float slA[5], slB[5], slC[5], slD[5];
    loadSlot(slA, offA); loadSlot(slB, offB2);
    loadSlot(slC, offC); loadSlot(slD, offD);

    for (int tb = 0; tb < nmax; tb += 4) {
        CSTEP4(slA, tb,     offA,  0)
        CSTEP4(slB, tb + 1, offB2, 0)
        CSTEP4(slC, tb + 2, offC,  0)
        CSTEP4(slD, tb + 3, offD,  1)   // renorm at t % 4 == 3
    }
}

__global__ __launch_bounds__(64, 1)
void crf_chain(const float* __restrict__ logits, const int* __restrict__ lens,
               const float* __restrict__ Tg, int B, int nz)
{
    if ((int)blockIdx.x < nz) chain4<0>(logits, lens, Tg, B, blockIdx.x);
    else                      chain4<1>(logits, lens, Tg, B, blockIdx.x - nz);
}

// Per sequence: P = sum_i Z_i * exp(logit_mid,i) * V_i ; norm = mf+mv+log P.
// Gold path score swept by all 64 lanes. One wave per sequence.
__global__ __launch_bounds__(64)
void crf_combine(const float* __restrict__ logits, const int* __restrict__ labels,
                 const int* __restrict__ lens, const float* __restrict__ T,
                 float* __restrict__ out, int B)
{
    const int b    = blockIdx.x;
    const int wtid = threadIdx.x;
    const int len  = lens[b];
    const int mid  = len >> 1;

    float prod = 0.0f;
    if (wtid < 17) {
        const float z  = g_Z[b * 17 + wtid];
        const float v  = g_V[b * 17 + wtid];
        const float lg = logits[(size_t)b * (S * NL) + mid * NL + wtid];
        prod = z * v * __expf(lg);
    }
    #pragma unroll
    for (int o = 32; o >= 1; o >>= 1) prod += __shfl_xor(prod, o);
    const float norm = g_mf[b] + g_mv[b] + __logf(prod);

    const int* labp = labels + b * S;
    float gsum = 0.0f;
    for (int c = 0; c < len; c += 64) {
        const int tok = c + wtid;
        if (tok < len) {
            const int lab = labp[tok];
            const int prv = (tok == 0) ? (L - 2) : labp[tok - 1];
            gsum += logits[(size_t)b * (S * NL) + tok * NL + lab] + T[lab * L + prv];
        }
    }
    #pragma unroll
    for (int o = 32; o >= 1; o >>= 1) gsum += __shfl_xor(gsum, o);
    const float gold = gsum + T[(L - 1) * L + labp[len - 1]];

    if (wtid == 0) out[b] = gold - norm;
}

extern "C" void kernel_launch(void* const* d_in, const int* in_sizes, int n_in,
                              void* d_out, int out_size, void* d_ws, size_t ws_size,
                              hipStream_t stream)
{
    (void)n_in; (void)out_size; (void)d_ws; (void)ws_size;
    const float* logits     = (const float*)d_in[0];
    const int*   labels     = (const int*)d_in[1];
    const int*   lens       = (const int*)d_in[2];
    const float* transition = (const float*)d_in[3];
    float*       out        = (float*)d_out;
    const int B  = in_sizes[2];
    const int NZ = (B + 15) / 16;

    crf_chain<<<dim3(2 * NZ), dim3(64), 0, stream>>>(logits, lens, transition, B, NZ);
    crf_combine<<<dim3(B), dim3(64), 0, stream>>>(logits, labels, lens, transition, out, B);
}